// Round 9
// baseline (524.112 us; speedup 1.0000x reference)
//
#include <hip/hip_runtime.h>
#include <stdint.h>

typedef __attribute__((ext_vector_type(8))) short short8;
typedef __attribute__((ext_vector_type(4))) float f32x4;

#define DEV __device__ __forceinline__

DEV float bits2f(uint32_t u){ union{uint32_t u;float f;}v; v.u=u; return v.f; }
DEV float bf1(uint16_t s){ return bits2f(((uint32_t)s)<<16); }
DEV uint16_t f2bf(float f){ union{float f;uint32_t u;}v; v.f=f; uint32_t u=v.u;
  return (uint16_t)((u + 0x7fffu + ((u>>16)&1u))>>16); }
DEV uint16_t f2h(float a){ union{_Float16 h; uint16_t u;}v; v.h=(_Float16)a; return v.u; }
DEV float h2f(uint16_t s){ union{uint16_t u; _Float16 h;}v; v.u=s; return (float)v.h; }

DEV float ldval(const float* p, size_t i){ return p[i]; }
DEV float ldval(const uint16_t* p, size_t i){ return bf1(p[i]); }
DEV void stval(float* p, size_t i, float v){ p[i]=v; }
DEV void stval(uint16_t* p, size_t i, float v){ p[i]=f2bf(v); }

DEV void async16(const void* g, void* l){
#if __has_builtin(__builtin_amdgcn_global_load_lds)
  __builtin_amdgcn_global_load_lds((const __attribute__((address_space(1))) void*)g,
                                   (__attribute__((address_space(3))) void*)l, 16, 0, 0);
#else
  int lane = threadIdx.x & 63;
  *(uint4*)((char*)l + lane*16) = *(const uint4*)((const char*)g);
#endif
}

// ---------------------------------------------------------------------------
// GEMM: C[M,N] = A[M,K] @ Bt[N,K]^T (+bias). Tile TM x TN, 4 waves of
// (TM/2)x(TN/2). R3 pipeline: 3-buffer BK=32 rotation, raw s_barrier,
// counted vmcnt (LPS-parameterized). R6 2-D XCD region map (gm>0) /
// 1-D column chunk (gm==0). R8: blocks lin >= nG run fused weight-transpose
// tiles (f32->bf16, 32x32 via LDS) in the latency-bound QKV dispatch.
// SPLIT: blockIdx.z K-chunking, fp32 partials at z*2560*N, no bias.
// ---------------------------------------------------------------------------
template<int TM, int TN, bool SPLIT>
__global__ __launch_bounds__(256) void gemm_t(
    const uint16_t* __restrict__ A, const uint16_t* __restrict__ Bt,
    const float* __restrict__ bias, void* __restrict__ Cout,
    int N, int K, int kchunk, int gm, int gx, int gy, int nG,
    const float* __restrict__ Tsrc1, const float* __restrict__ Tsrc2,
    uint16_t* __restrict__ Tdst1, uint16_t* __restrict__ Tdst2) {
  __shared__ uint16_t sA[3][TM*32];
  __shared__ uint16_t sB[3][TN*32];
  constexpr int LPS = TM/64 + TN/64;   // global_load_lds per thread per stage
  const int tid = threadIdx.x;
  const int lin = blockIdx.y*gx + blockIdx.x;

  if (lin >= nG) {                     // ---- fused weight transpose tile ----
    float (*t)[33] = (float(*)[33])&sA[0][0];
    int tt = lin - nG;
    const float* src; uint16_t* dst; int R, C, c0, r0;
    if (tt < 4096) { src = Tsrc1; dst = Tdst1; R = 1024; C = 4096;
                     c0 = (tt&127)*32; r0 = (tt>>7)*32; }
    else { tt -= 4096; src = Tsrc2; dst = Tdst2; R = 4096; C = 1024;
           c0 = (tt&31)*32; r0 = (tt>>5)*32; }
    const int tx = tid&31, ty = tid>>5;
    #pragma unroll
    for (int i=0;i<4;i++) t[ty+8*i][tx] = src[(size_t)(r0+ty+8*i)*C + c0+tx];
    __syncthreads();
    #pragma unroll
    for (int i=0;i<4;i++) dst[(size_t)(c0+ty+8*i)*R + r0+tx] = f2bf(t[tx][ty+8*i]);
    return;
  }

  int mt_, nt_;
  if (gm > 0) {
    const int xcd = lin & 7, idx = lin >> 3;
    const int RM = gy / gm;
    const int RN = (gx * gm) >> 3;
    const int rm = xcd % gm, rn = xcd / gm;
    mt_ = rm*RM + idx % RM;
    nt_ = rn*RN + idx / RM;
  } else {
    const int q8 = (gx*gy) >> 3;
    const int swz = (lin & 7)*q8 + (lin >> 3);
    mt_ = swz % gy; nt_ = swz / gy;
  }
  const int m0 = mt_*TM, n0 = nt_*TN;
  const int kb = SPLIT ? blockIdx.z*kchunk : 0;
  const int kend = SPLIT ? kb + kchunk : K;
  const int wid = tid>>6, lane = tid&63;
  constexpr int WM = TM/2, MT = WM/16;
  constexpr int WN = TN/2, NT = WN/16;
  const int wm = (wid&1)*WM, wn = (wid>>1)*WN;
  f32x4 acc[MT][NT];
  #pragma unroll
  for (int a=0;a<MT;a++)
    #pragma unroll
    for (int b=0;b<NT;b++) acc[a][b] = (f32x4){0.f,0.f,0.f,0.f};
  const int lrow = lane>>2;
  const int lcol = (((lane&3) ^ ((lrow>>1)&3)))*8;
  const int fr = lane&15, fc = lane>>4;
  const int rsw = (fc ^ ((fr>>1)&3))*8;    // swizzled read slot

  auto stage = [&](int buf, int k0) {
    #pragma unroll
    for (int j = 0; j < TM/64; ++j) {
      int r0 = wid*(TM/4) + j*16;
      async16(A + (size_t)(m0+r0+lrow)*K + k0 + lcol, &sA[buf][r0*32]);
    }
    #pragma unroll
    for (int j = 0; j < TN/64; ++j) {
      int r0 = wid*(TN/4) + j*16;
      async16(Bt + (size_t)(n0+r0+lrow)*K + k0 + lcol, &sB[buf][r0*32]);
    }
  };

  const int niter = (kend - kb) >> 5;
  stage(0, kb);
  if (niter > 1) stage(1, kb + 32);
  int cur = 0;
  for (int it = 0; it < niter; ++it) {
    if (it+1 < niter) {
      if constexpr (LPS == 4)      asm volatile("s_waitcnt vmcnt(4)" ::: "memory");
      else if constexpr (LPS == 3) asm volatile("s_waitcnt vmcnt(3)" ::: "memory");
      else                         asm volatile("s_waitcnt vmcnt(2)" ::: "memory");
    } else {
      asm volatile("s_waitcnt vmcnt(0)" ::: "memory");
    }
    __builtin_amdgcn_s_barrier();
    __builtin_amdgcn_sched_barrier(0);
    if (it+2 < niter) {
      int b2 = cur+2; if (b2>=3) b2-=3;
      stage(b2, kb + (it+2)*32);
    }
    short8 af[MT], bfv[NT];
    #pragma unroll
    for (int t=0;t<MT;t++) af[t] = *(const short8*)&sA[cur][(wm + t*16 + fr)*32 + rsw];
    #pragma unroll
    for (int t=0;t<NT;t++) bfv[t] = *(const short8*)&sB[cur][(wn + t*16 + fr)*32 + rsw];
    #pragma unroll
    for (int mt=0;mt<MT;mt++)
      #pragma unroll
      for (int nt=0;nt<NT;nt++)
        acc[mt][nt] = __builtin_amdgcn_mfma_f32_16x16x32_bf16(af[mt], bfv[nt], acc[mt][nt], 0,0,0);
    if (++cur == 3) cur = 0;
  }
  const int cl = lane&15, rl = (lane>>4)*4;   // C/D: col=lane&15, row=(lane>>4)*4+reg
  if (SPLIT) {
    float* Pz = (float*)Cout + (size_t)blockIdx.z*2560*N;
    #pragma unroll
    for (int nt=0;nt<NT;nt++) {
      int n = n0 + wn + nt*16 + cl;
      #pragma unroll
      for (int mt=0;mt<MT;mt++)
        #pragma unroll
        for (int r=0;r<4;r++)
          Pz[(size_t)(m0 + wm + mt*16 + rl + r)*N + n] = acc[mt][nt][r];
    }
  } else {
    uint16_t* C = (uint16_t*)Cout;
    #pragma unroll
    for (int nt=0;nt<NT;nt++) {
      int n = n0 + wn + nt*16 + cl;
      float bv = bias ? bias[n] : 0.f;
      #pragma unroll
      for (int mt=0;mt<MT;mt++)
        #pragma unroll
        for (int r=0;r<4;r++)
          C[(size_t)(m0 + wm + mt*16 + rl + r)*N + n] = f2bf(acc[mt][nt][r] + bv);
    }
  }
}

// ---------------------------------------------------------------------------
// LayerNorm body (256-thread flat block, one row of D=1024).
// ---------------------------------------------------------------------------
template<typename TI, typename TO>
DEV void ln_body(int row, int tid, const TI* x, const float* sc, const float* bi,
                 TO* out, float* red) {
  const size_t base = (size_t)row*1024 + tid*4;
  float v0=ldval(x,base), v1=ldval(x,base+1), v2=ldval(x,base+2), v3=ldval(x,base+3);
  float s = v0+v1+v2+v3;
  float sq = v0*v0+v1*v1+v2*v2+v3*v3;
  #pragma unroll
  for (int off=32; off; off>>=1){ s += __shfl_xor(s,off); sq += __shfl_xor(sq,off); }
  int wid=tid>>6, lane=tid&63;
  if (lane==0){ red[wid]=s; red[4+wid]=sq; }
  __syncthreads();
  s = red[0]+red[1]+red[2]+red[3]; sq = red[4]+red[5]+red[6]+red[7];
  float mean = s*(1.f/1024.f);
  float inv  = rsqrtf(sq*(1.f/1024.f) - mean*mean + 1e-5f);
  int c = tid*4;
  stval(out, base,   (v0-mean)*inv*sc[c]   + bi[c]);
  stval(out, base+1, (v1-mean)*inv*sc[c+1] + bi[c+1]);
  stval(out, base+2, (v2-mean)*inv*sc[c+2] + bi[c+2]);
  stval(out, base+3, (v3-mean)*inv*sc[c+3] + bi[c+3]);
}

template<typename TI, typename TO>
__global__ __launch_bounds__(256) void ln_k(const TI* __restrict__ x,
    const float* __restrict__ sc, const float* __restrict__ bi,
    TO* __restrict__ out) {
  __shared__ float red[8];
  ln_body<TI,TO>(blockIdx.x, threadIdx.x, x, sc, bi, out, red);
}

// Fused: y = P[0][row]+P[1][row] + b2 + resid(bf16); out = LN(y).
template<typename TO>
__global__ __launch_bounds__(256) void ln2_fused(const float* __restrict__ P,
    const float* __restrict__ b2, const uint16_t* __restrict__ resid,
    const float* __restrict__ sc, const float* __restrict__ bi,
    TO* __restrict__ out) {
  const int row = blockIdx.x, tid = threadIdx.x;
  const size_t base = (size_t)row*1024 + tid*4;
  float4 p0 = *(const float4*)(P + base);
  float4 p1 = *(const float4*)(P + (size_t)2560*1024 + base);
  int c = tid*4;
  float v0 = p0.x+p1.x+b2[c]  +bf1(resid[base]);
  float v1 = p0.y+p1.y+b2[c+1]+bf1(resid[base+1]);
  float v2 = p0.z+p1.z+b2[c+2]+bf1(resid[base+2]);
  float v3 = p0.w+p1.w+b2[c+3]+bf1(resid[base+3]);
  float s = v0+v1+v2+v3;
  float sq = v0*v0+v1*v1+v2*v2+v3*v3;
  #pragma unroll
  for (int off=32; off; off>>=1){ s += __shfl_xor(s,off); sq += __shfl_xor(sq,off); }
  __shared__ float red[8];
  int wid=tid>>6, lane=tid&63;
  if (lane==0){ red[wid]=s; red[4+wid]=sq; }
  __syncthreads();
  s = red[0]+red[1]+red[2]+red[3]; sq = red[4]+red[5]+red[6]+red[7];
  float mean = s*(1.f/1024.f);
  float inv  = rsqrtf(sq*(1.f/1024.f) - mean*mean + 1e-5f);
  stval(out, base,   (v0-mean)*inv*sc[c]   + bi[c]);
  stval(out, base+1, (v1-mean)*inv*sc[c+1] + bi[c+1]);
  stval(out, base+2, (v2-mean)*inv*sc[c+2] + bi[c+2]);
  stval(out, base+3, (v3-mean)*inv*sc[c+3] + bi[c+3]);
}

// ---------------------------------------------------------------------------
// Fused Emformer attention, bf16 MFMA end-to-end. Closed-form mask.
// R9: qg-merge. Block = (bb,hh,ci) only (256 blocks). K and V staged ONCE
// (was 4x across qg blocks); Q double-buffered; loop qg=0..3 through
// {QK^T -> S-write -> softmax -> PV -> epilogue}. LDS 114,688 B static
// (K[288][72] 41.5K @0 | V[288][66] 38K @41472B | S[40][296] 23.7K @79488B
//  | Q[2][40][72] 11.5K @103168B) -> 1 block/CU; 256 blocks = 1 generation.
// Barriers: 1 initial + 3/qg. Top-of-loop barrier covers {prev PV P-reads
// done before S overwrite; Q[qg] ds_writes visible}. Q[qg+1] staged into the
// other buffer right after the top barrier (disjoint from QK's Q[qg] reads).
// S region is disjoint from K/Q/V so QK -> S-write needs no barrier.
// ---------------------------------------------------------------------------
__global__ __launch_bounds__(256) void attn_fused(
    const uint32_t* __restrict__ qkv32, const uint16_t* __restrict__ hres,
    uint16_t* __restrict__ attn_out) {
  const int blk = blockIdx.x;
  const int ci = blk&7, hh = (blk>>3)&15, bb = blk>>7;
  const int sum_cnt = (ci<7)?32:0;
  const int bstart = (ci>=1)?128*(ci-1):0;
  const int bend = (ci==7)?1024:128*(ci+1);
  const int nk = sum_cnt + (bend - bstart);
  const int rowbase = bb*1248;
  const int tid = threadIdx.x, wid = tid>>6, lane = tid&63;
  const int fr = lane&15, fc = lane>>4;

  __shared__ __attribute__((aligned(16))) uint16_t sm[57344];  // 114,688 B
  uint16_t* K16 = sm;                        // [nk][72] bf16, stride 36 dw
  uint32_t* KD  = (uint32_t*)sm;
  uint16_t* V16 = sm + 20736;                // [nk][66] bf16, stride 33 dw
  uint32_t* VD  = (uint32_t*)(sm + 20736);
  uint16_t* SP16 = sm + 39744;               // S f16 / P bf16 [40][296]
  uint16_t* Q16 = sm + 51584;                // [2][40][72] bf16
  uint32_t* QD  = (uint32_t*)(sm + 51584);   // per-buffer 1440 dw

  // ---- stage K, V, Q[0] once ----
  for (int idx = tid; idx < nk*8; idx += 256) {
    int j = idx>>3, q4 = idx&7;
    int tk = (j < sum_cnt) ? (32*ci + j) : (224 + bstart + (j - sum_cnt));
    *(uint4*)&KD[j*36 + q4*4] =
      *(const uint4*)&qkv32[(size_t)(rowbase+tk)*1536 + 512 + hh*32 + q4*4];
  }
  for (int idx = tid; idx < nk*8; idx += 256) {
    int j = idx>>3, q4 = idx&7;
    int tk = (j < sum_cnt) ? (32*ci + j) : (224 + bstart + (j - sum_cnt));
    uint4 w = *(const uint4*)&qkv32[(size_t)(rowbase+tk)*1536 + 1024 + hh*32 + q4*4];
    uint32_t* dst = &VD[j*33 + q4*4];
    dst[0]=w.x; dst[1]=w.y; dst[2]=w.z; dst[3]=w.w;
  }
  for (int idx = tid; idx < 40*8; idx += 256) {
    int j = idx>>3, q4 = idx&7;
    int tq = (j<32) ? (32*ci+j) : (224+128*ci+j-32);
    *(uint4*)&QD[j*36 + q4*4] =
      *(const uint4*)&qkv32[(size_t)(rowbase+tq)*1536 + hh*32 + q4*4];
  }

  const int n_mt = nk>>4;
  const int nkt = nk>>5;
  const int qoff[3] = {0,16,24};

  for (int qg = 0; qg < 4; ++qg) {
    __syncthreads();   // staging/prev-PV/Q[qg] writes all visible

    // stage Q[qg+1] into the other buffer (disjoint from QK's reads)
    if (qg < 3) {
      const int qb = (qg+1)&1;
      for (int idx = tid; idx < 40*8; idx += 256) {
        int j = idx>>3, q4 = idx&7;
        int ql = (qg+1)*40 + j;
        int tq = (ql<32) ? (32*ci+ql) : (224+128*ci+ql-32);
        *(uint4*)&QD[qb*1440 + j*36 + q4*4] =
          *(const uint4*)&qkv32[(size_t)(rowbase+tq)*1536 + hh*32 + q4*4];
      }
    }

    // ---- scores: S^T = K . Q^T (m=key, n=query, k=d) ----
    const uint16_t* Qb = Q16 + (qg&1)*2880;
    f32x4 accs[5][3];
    #pragma unroll
    for (int a=0;a<5;a++)
      #pragma unroll
      for (int b=0;b<3;b++) accs[a][b] = (f32x4){0.f,0.f,0.f,0.f};
    __builtin_amdgcn_s_setprio(1);
    #pragma unroll
    for (int ks=0; ks<2; ++ks) {
      short8 bq_[3];
      #pragma unroll
      for (int nt=0;nt<3;nt++)
        bq_[nt] = *(const short8*)&Qb[(qoff[nt]+fr)*72 + ks*32 + fc*8];
      #pragma unroll
      for (int t=0;t<5;t++) {
        int mt = wid + 4*t;
        if (mt < n_mt) {
          short8 a_ = *(const short8*)&K16[(mt*16+fr)*72 + ks*32 + fc*8];
          #pragma unroll
          for (int nt=0;nt<3;nt++)
            accs[t][nt] = __builtin_amdgcn_mfma_f32_16x16x32_bf16(a_, bq_[nt], accs[t][nt], 0,0,0);
        }
      }
    }
    __builtin_amdgcn_s_setprio(0);

    // ---- S <- C-frags (f16); S region disjoint, no barrier needed ----
    #pragma unroll
    for (int t=0;t<5;t++) {
      int mt = wid + 4*t;
      if (mt < n_mt) {
        #pragma unroll
        for (int nt=0;nt<3;nt++) {
          int q = qoff[nt] + fr;
          #pragma unroll
          for (int r=0;r<4;r++)
            SP16[q*296 + mt*16 + fc*4 + r] = f2h(accs[t][nt][r]*0.125f);
        }
      }
    }
    __syncthreads();

    // ---- softmax rows, in place: S(f16) -> P(bf16) ----
    for (int i=0;i<10;i++) {
      int row = wid*10 + i;
      float v[5];
      #pragma unroll
      for (int g2=0;g2<5;g2++){ int k=g2*64+lane; v[g2] = (k<nk) ? h2f(SP16[row*296+k]) : -1e30f; }
      float mx = fmaxf(fmaxf(fmaxf(v[0],v[1]),fmaxf(v[2],v[3])),v[4]);
      #pragma unroll
      for (int off=32; off; off>>=1) mx = fmaxf(mx, __shfl_xor(mx,off));
      float p[5], sum=0.f;
      #pragma unroll
      for (int g2=0;g2<5;g2++){ p[g2] = __expf(v[g2]-mx); if (g2*64+lane>=nk) p[g2]=0.f; sum+=p[g2]; }
      #pragma unroll
      for (int off=32; off; off>>=1) sum += __shfl_xor(sum,off);
      float inv = 1.f/sum;
      #pragma unroll
      for (int g2=0;g2<5;g2++){ int k=g2*64+lane; if (k<nk) SP16[row*296+k] = f2bf(p[g2]*inv); }
    }
    __syncthreads();

    // ---- O = P . V  (m=query, n=d [wave-owned 16], k=key) ----
    f32x4 acco[3];
    #pragma unroll
    for (int t=0;t<3;t++) acco[t] = (f32x4){0.f,0.f,0.f,0.f};
    const uint16_t* vcol = V16 + wid*16 + fr;
    __builtin_amdgcn_s_setprio(1);
    for (int kt=0; kt<nkt; ++kt) {
      short8 bv_;
      #pragma unroll
      for (int j=0;j<8;j++) bv_[j] = (short)vcol[(kt*32 + fc*8 + j)*66];
      #pragma unroll
      for (int t=0;t<3;t++) {
        short8 a_ = *(const short8*)&SP16[(qoff[t]+fr)*296 + kt*32 + fc*8];
        acco[t] = __builtin_amdgcn_mfma_f32_16x16x32_bf16(a_, bv_, acco[t], 0,0,0);
      }
    }
    __builtin_amdgcn_s_setprio(0);

    // ---- epilogue: + residual (C col = d, row = query) ----
    #pragma unroll
    for (int t=0;t<3;t++) {
      #pragma unroll
      for (int r=0;r<4;r++) {
        bool vq = true;
        if (ci==7 && qg==0 && (qoff[t]+fc*4+r)<32) vq = false;
        if (vq) {
          int qll = qg*40 + qoff[t] + fc*4 + r;
          int tq = (qll<32) ? (32*ci+qll) : (224+128*ci+qll-32);
          size_t addr = (size_t)(rowbase+tq)*1024 + hh*64 + wid*16 + fr;
          attn_out[addr] = f2bf(acco[t][r] + bf1(hres[addr]));
        }
      }
    }
  }
}

// ---------------------------------------------------------------------------
// R8 layer prologue (shrunk): QKV weight transposes (blocks 0..3071), bias
// concat (3072..3083), input LayerNorm rows (3084..5579).
// ---------------------------------------------------------------------------
__global__ void prep_k(const float* __restrict__ Wq, const float* __restrict__ Wk,
                       const float* __restrict__ Wv, const float* __restrict__ bq,
                       const float* __restrict__ bk, const float* __restrict__ bv,
                       uint16_t* __restrict__ wt_qkv, float* __restrict__ bqkv,
                       const void* __restrict__ lnx, int lnx_f32,
                       const float* __restrict__ lnsc, const float* __restrict__ lnbi,
                       uint16_t* __restrict__ lnout) {
  __shared__ float t[32][33];
  const int blk = blockIdx.x;
  const int tx = threadIdx.x, ty = threadIdx.y;
  if (blk >= 3084) {                        // LayerNorm rows
    int row = blk - 3084;
    int tid = ty*32 + tx;
    float* red = &t[0][0];
    if (lnx_f32) ln_body<float,uint16_t>((int)row, tid, (const float*)lnx, lnsc, lnbi, lnout, red);
    else         ln_body<uint16_t,uint16_t>((int)row, tid, (const uint16_t*)lnx, lnsc, lnbi, lnout, red);
    return;
  }
  if (blk >= 3072) {                        // bias concat
    int i = (blk-3072)*256 + ty*32 + tx;
    bqkv[i] = (i<1024) ? bq[i] : ((i<2048) ? bk[i-1024] : bv[i-2048]);
    return;
  }
  int w = blk>>10, tt = blk&1023;
  const float* src = (w==0)?Wq:((w==1)?Wk:Wv);
  uint16_t* dst = wt_qkv + (size_t)w*1048576;
  const int R = 1024, C = 1024;
  const int c0 = (tt&31)*32, r0 = (tt>>5)*32;
  #pragma unroll
  for (int i=0;i<4;i++) t[ty+8*i][tx] = src[(size_t)(r0+ty+8*i)*C + c0+tx];
  __syncthreads();
  #pragma unroll
  for (int i=0;i<4;i++) dst[(size_t)(c0+ty+8*i)*R + r0+tx] = f2bf(t[tx][ty+8*i]);
}

// ---------------------------------------------------------------------------
extern "C" void kernel_launch(void* const* d_in, const int* in_sizes, int n_in,
                              void* d_out, int out_size, void* d_ws, size_t ws_size,
                              hipStream_t stream) {
  const float* input  = (const float*)d_in[0];
  const float* lnin_s = (const float*)d_in[1];
  const float* lnin_b = (const float*)d_in[2];
  const float* Wq = (const float*)d_in[3];
  const float* bq = (const float*)d_in[4];
  const float* Wk = (const float*)d_in[5];
  const float* bk = (const float*)d_in[6];
  const float* Wv = (const float*)d_in[7];
  const float* bv = (const float*)d_in[8];
  const float* ln1_s = (const float*)d_in[9];
  const float* ln1_b = (const float*)d_in[10];
  const float* W1 = (const float*)d_in[11];
  const float* b1 = (const float*)d_in[12];
  const float* W2 = (const float*)d_in[13];
  const float* b2 = (const float*)d_in[14];
  const float* ln2_s = (const float*)d_in[15];
  const float* ln2_b = (const float*)d_in[16];
  // mask d_in[17] unused: Emformer mask is closed-form.

  char* ws = (char*)d_ws;
  uint16_t* wt_qkv = (uint16_t*)(ws + 0);         // bf16 [3072][1024]
  uint16_t* wt_w1  = (uint16_t*)(ws + 6291456);   // bf16 [4096][1024]
  uint16_t* wt_w2  = (uint16_t*)(ws + 14680064);  // bf16 [1024][4096]
  float*    bqkv   = (float*)   (ws + 23068672);  // f32  [3072]
  uint16_t* hbuf   = (uint16_t*)(ws + 23080960);  // bf16 [2560][1024]
  uint16_t* qkvb   = (uint16_t*)(ws + 28323840);  // bf16 [2560][3072]
  uint16_t* attnb  = (uint16_t*)(ws + 44052480);  // bf16 [2560][1024]
  uint16_t* zbuf   = (uint16_t*)(ws + 49295360);  // bf16 [2560][1024]
  float*    pbuf   = (float*)   (ws + 54538240);  // fp32 [2][2560][1024]
  uint16_t* y1b    = hbuf;                        // bf16 [2560][4096] overlays hbuf+qkvb (dead)
  uint16_t* x1b    = zbuf;                        // layer-0 out overlays zbuf (audited r4)
  // peak ws usage: 75,509,760 bytes

  const uint16_t* xcur_bf = x1b;
  for (int l=0; l<2; ++l) {
    prep_k<<<5580, dim3(32,8), 0, stream>>>(Wq+(size_t)l*1048576, Wk+(size_t)l*1048576,
        Wv+(size_t)l*1048576, bq+l*1024, bk+l*1024, bv+l*1024, wt_qkv, bqkv,
        (l==0) ? (const void*)input : (const void*)xcur_bf, (l==0)?1:0,
        lnin_s+l*1024, lnin_b+l*1024, hbuf);

    // QKV GEMM (480 blocks, gm=2 region map) + fused W1/W2 transposes
    gemm_t<128,128,false><<<dim3(8672),256,0,stream>>>(hbuf, wt_qkv, bqkv, qkvb,
        3072, 1024, 0, 2, 24, 20, 480,
        W1+(size_t)l*4194304, W2+(size_t)l*4194304, wt_w1, wt_w2);
    attn_fused<<<256,256,0,stream>>>((const uint32_t*)qkvb, hbuf, attnb);
    ln_k<uint16_t,uint16_t><<<2496,256,0,stream>>>(attnb, ln1_s+l*1024, ln1_b+l*1024, zbuf);
    // W1: grid 32x20, gm=2 (RM=10, RN=8)
    gemm_t<128,128,false><<<dim3(32,20),256,0,stream>>>(zbuf, wt_w1, b1+l*4096, y1b,
        4096, 1024, 0, 2, 32, 20, 640, nullptr, nullptr, nullptr, nullptr);
    // W2: 128x64 split z=2, legacy 1-D swizzle
    gemm_t<128,64,true><<<dim3(16,20,2),256,0,stream>>>(y1b, wt_w2, nullptr, pbuf,
        1024, 4096, 2048, 0, 16, 20, 320, nullptr, nullptr, nullptr, nullptr);
    if (l==1) ln2_fused<float>   <<<2496,256,0,stream>>>(pbuf, b2+l*1024, attnb, ln2_s+l*1024, ln2_b+l*1024, (float*)d_out);
    else      ln2_fused<uint16_t><<<2496,256,0,stream>>>(pbuf, b2+l*1024, attnb, ln2_s+l*1024, ln2_b+l*1024, x1b);
  }
  (void)in_sizes; (void)n_in; (void)out_size; (void)ws_size;
}

// Round 10
// 481.594 us; speedup vs baseline: 1.0883x; 1.0883x over previous
//
#include <hip/hip_runtime.h>
#include <stdint.h>

typedef __attribute__((ext_vector_type(8))) short short8;
typedef __attribute__((ext_vector_type(4))) float f32x4;

#define DEV __device__ __forceinline__

DEV float bits2f(uint32_t u){ union{uint32_t u;float f;}v; v.u=u; return v.f; }
DEV float bf1(uint16_t s){ return bits2f(((uint32_t)s)<<16); }
DEV uint16_t f2bf(float f){ union{float f;uint32_t u;}v; v.f=f; uint32_t u=v.u;
  return (uint16_t)((u + 0x7fffu + ((u>>16)&1u))>>16); }
DEV uint16_t f2h(float a){ union{_Float16 h; uint16_t u;}v; v.h=(_Float16)a; return v.u; }
DEV float h2f(uint16_t s){ union{uint16_t u; _Float16 h;}v; v.u=s; return (float)v.h; }

DEV float ldval(const float* p, size_t i){ return p[i]; }
DEV float ldval(const uint16_t* p, size_t i){ return bf1(p[i]); }
DEV void stval(float* p, size_t i, float v){ p[i]=v; }
DEV void stval(uint16_t* p, size_t i, float v){ p[i]=f2bf(v); }

DEV void async16(const void* g, void* l){
#if __has_builtin(__builtin_amdgcn_global_load_lds)
  __builtin_amdgcn_global_load_lds((const __attribute__((address_space(1))) void*)g,
                                   (__attribute__((address_space(3))) void*)l, 16, 0, 0);
#else
  int lane = threadIdx.x & 63;
  *(uint4*)((char*)l + lane*16) = *(const uint4*)((const char*)g);
#endif
}

// ---------------------------------------------------------------------------
// GEMM: C[M,N] = A[M,K] @ Bt[N,K]^T (+bias). Tile TM x TN, 4 waves of
// (TM/2)x(TN/2). R3 pipeline: 3-buffer BK=32 rotation, raw s_barrier,
// counted vmcnt (LPS-parameterized). R6 2-D XCD region map (gm>0) /
// 1-D column chunk (gm==0). R8: blocks lin >= nG run fused weight-transpose
// tiles (f32->bf16, 32x32 via LDS) in the latency-bound QKV dispatch.
// SPLIT: blockIdx.z K-chunking, fp32 partials at z*2560*N, no bias.
// ---------------------------------------------------------------------------
template<int TM, int TN, bool SPLIT>
__global__ __launch_bounds__(256) void gemm_t(
    const uint16_t* __restrict__ A, const uint16_t* __restrict__ Bt,
    const float* __restrict__ bias, void* __restrict__ Cout,
    int N, int K, int kchunk, int gm, int gx, int gy, int nG,
    const float* __restrict__ Tsrc1, const float* __restrict__ Tsrc2,
    uint16_t* __restrict__ Tdst1, uint16_t* __restrict__ Tdst2) {
  __shared__ uint16_t sA[3][TM*32];
  __shared__ uint16_t sB[3][TN*32];
  constexpr int LPS = TM/64 + TN/64;   // global_load_lds per thread per stage
  const int tid = threadIdx.x;
  const int lin = blockIdx.y*gx + blockIdx.x;

  if (lin >= nG) {                     // ---- fused weight transpose tile ----
    float (*t)[33] = (float(*)[33])&sA[0][0];
    int tt = lin - nG;
    const float* src; uint16_t* dst; int R, C, c0, r0;
    if (tt < 4096) { src = Tsrc1; dst = Tdst1; R = 1024; C = 4096;
                     c0 = (tt&127)*32; r0 = (tt>>7)*32; }
    else { tt -= 4096; src = Tsrc2; dst = Tdst2; R = 4096; C = 1024;
           c0 = (tt&31)*32; r0 = (tt>>5)*32; }
    const int tx = tid&31, ty = tid>>5;
    #pragma unroll
    for (int i=0;i<4;i++) t[ty+8*i][tx] = src[(size_t)(r0+ty+8*i)*C + c0+tx];
    __syncthreads();
    #pragma unroll
    for (int i=0;i<4;i++) dst[(size_t)(c0+ty+8*i)*R + r0+tx] = f2bf(t[tx][ty+8*i]);
    return;
  }

  int mt_, nt_;
  if (gm > 0) {
    const int xcd = lin & 7, idx = lin >> 3;
    const int RM = gy / gm;
    const int RN = (gx * gm) >> 3;
    const int rm = xcd % gm, rn = xcd / gm;
    mt_ = rm*RM + idx % RM;
    nt_ = rn*RN + idx / RM;
  } else {
    const int q8 = (gx*gy) >> 3;
    const int swz = (lin & 7)*q8 + (lin >> 3);
    mt_ = swz % gy; nt_ = swz / gy;
  }
  const int m0 = mt_*TM, n0 = nt_*TN;
  const int kb = SPLIT ? blockIdx.z*kchunk : 0;
  const int kend = SPLIT ? kb + kchunk : K;
  const int wid = tid>>6, lane = tid&63;
  constexpr int WM = TM/2, MT = WM/16;
  constexpr int WN = TN/2, NT = WN/16;
  const int wm = (wid&1)*WM, wn = (wid>>1)*WN;
  f32x4 acc[MT][NT];
  #pragma unroll
  for (int a=0;a<MT;a++)
    #pragma unroll
    for (int b=0;b<NT;b++) acc[a][b] = (f32x4){0.f,0.f,0.f,0.f};
  const int lrow = lane>>2;
  const int lcol = (((lane&3) ^ ((lrow>>1)&3)))*8;
  const int fr = lane&15, fc = lane>>4;
  const int rsw = (fc ^ ((fr>>1)&3))*8;    // swizzled read slot

  auto stage = [&](int buf, int k0) {
    #pragma unroll
    for (int j = 0; j < TM/64; ++j) {
      int r0 = wid*(TM/4) + j*16;
      async16(A + (size_t)(m0+r0+lrow)*K + k0 + lcol, &sA[buf][r0*32]);
    }
    #pragma unroll
    for (int j = 0; j < TN/64; ++j) {
      int r0 = wid*(TN/4) + j*16;
      async16(Bt + (size_t)(n0+r0+lrow)*K + k0 + lcol, &sB[buf][r0*32]);
    }
  };

  const int niter = (kend - kb) >> 5;
  stage(0, kb);
  if (niter > 1) stage(1, kb + 32);
  int cur = 0;
  for (int it = 0; it < niter; ++it) {
    if (it+1 < niter) {
      if constexpr (LPS == 4)      asm volatile("s_waitcnt vmcnt(4)" ::: "memory");
      else if constexpr (LPS == 3) asm volatile("s_waitcnt vmcnt(3)" ::: "memory");
      else                         asm volatile("s_waitcnt vmcnt(2)" ::: "memory");
    } else {
      asm volatile("s_waitcnt vmcnt(0)" ::: "memory");
    }
    __builtin_amdgcn_s_barrier();
    __builtin_amdgcn_sched_barrier(0);
    if (it+2 < niter) {
      int b2 = cur+2; if (b2>=3) b2-=3;
      stage(b2, kb + (it+2)*32);
    }
    short8 af[MT], bfv[NT];
    #pragma unroll
    for (int t=0;t<MT;t++) af[t] = *(const short8*)&sA[cur][(wm + t*16 + fr)*32 + rsw];
    #pragma unroll
    for (int t=0;t<NT;t++) bfv[t] = *(const short8*)&sB[cur][(wn + t*16 + fr)*32 + rsw];
    #pragma unroll
    for (int mt=0;mt<MT;mt++)
      #pragma unroll
      for (int nt=0;nt<NT;nt++)
        acc[mt][nt] = __builtin_amdgcn_mfma_f32_16x16x32_bf16(af[mt], bfv[nt], acc[mt][nt], 0,0,0);
    if (++cur == 3) cur = 0;
  }
  const int cl = lane&15, rl = (lane>>4)*4;   // C/D: col=lane&15, row=(lane>>4)*4+reg
  if (SPLIT) {
    float* Pz = (float*)Cout + (size_t)blockIdx.z*2560*N;
    #pragma unroll
    for (int nt=0;nt<NT;nt++) {
      int n = n0 + wn + nt*16 + cl;
      #pragma unroll
      for (int mt=0;mt<MT;mt++)
        #pragma unroll
        for (int r=0;r<4;r++)
          Pz[(size_t)(m0 + wm + mt*16 + rl + r)*N + n] = acc[mt][nt][r];
    }
  } else {
    uint16_t* C = (uint16_t*)Cout;
    #pragma unroll
    for (int nt=0;nt<NT;nt++) {
      int n = n0 + wn + nt*16 + cl;
      float bv = bias ? bias[n] : 0.f;
      #pragma unroll
      for (int mt=0;mt<MT;mt++)
        #pragma unroll
        for (int r=0;r<4;r++)
          C[(size_t)(m0 + wm + mt*16 + rl + r)*N + n] = f2bf(acc[mt][nt][r] + bv);
    }
  }
}

// ---------------------------------------------------------------------------
// LayerNorm body (256-thread flat block, one row of D=1024).
// ---------------------------------------------------------------------------
template<typename TI, typename TO>
DEV void ln_body(int row, int tid, const TI* x, const float* sc, const float* bi,
                 TO* out, float* red) {
  const size_t base = (size_t)row*1024 + tid*4;
  float v0=ldval(x,base), v1=ldval(x,base+1), v2=ldval(x,base+2), v3=ldval(x,base+3);
  float s = v0+v1+v2+v3;
  float sq = v0*v0+v1*v1+v2*v2+v3*v3;
  #pragma unroll
  for (int off=32; off; off>>=1){ s += __shfl_xor(s,off); sq += __shfl_xor(sq,off); }
  int wid=tid>>6, lane=tid&63;
  if (lane==0){ red[wid]=s; red[4+wid]=sq; }
  __syncthreads();
  s = red[0]+red[1]+red[2]+red[3]; sq = red[4]+red[5]+red[6]+red[7];
  float mean = s*(1.f/1024.f);
  float inv  = rsqrtf(sq*(1.f/1024.f) - mean*mean + 1e-5f);
  int c = tid*4;
  stval(out, base,   (v0-mean)*inv*sc[c]   + bi[c]);
  stval(out, base+1, (v1-mean)*inv*sc[c+1] + bi[c+1]);
  stval(out, base+2, (v2-mean)*inv*sc[c+2] + bi[c+2]);
  stval(out, base+3, (v3-mean)*inv*sc[c+3] + bi[c+3]);
}

template<typename TI, typename TO>
__global__ __launch_bounds__(256) void ln_k(const TI* __restrict__ x,
    const float* __restrict__ sc, const float* __restrict__ bi,
    TO* __restrict__ out) {
  __shared__ float red[8];
  ln_body<TI,TO>(blockIdx.x, threadIdx.x, x, sc, bi, out, red);
}

// Fused: y = P[0][row]+P[1][row] + b2 + resid(bf16); out = LN(y).
template<typename TO>
__global__ __launch_bounds__(256) void ln2_fused(const float* __restrict__ P,
    const float* __restrict__ b2, const uint16_t* __restrict__ resid,
    const float* __restrict__ sc, const float* __restrict__ bi,
    TO* __restrict__ out) {
  const int row = blockIdx.x, tid = threadIdx.x;
  const size_t base = (size_t)row*1024 + tid*4;
  float4 p0 = *(const float4*)(P + base);
  float4 p1 = *(const float4*)(P + (size_t)2560*1024 + base);
  int c = tid*4;
  float v0 = p0.x+p1.x+b2[c]  +bf1(resid[base]);
  float v1 = p0.y+p1.y+b2[c+1]+bf1(resid[base+1]);
  float v2 = p0.z+p1.z+b2[c+2]+bf1(resid[base+2]);
  float v3 = p0.w+p1.w+b2[c+3]+bf1(resid[base+3]);
  float s = v0+v1+v2+v3;
  float sq = v0*v0+v1*v1+v2*v2+v3*v3;
  #pragma unroll
  for (int off=32; off; off>>=1){ s += __shfl_xor(s,off); sq += __shfl_xor(sq,off); }
  __shared__ float red[8];
  int wid=tid>>6, lane=tid&63;
  if (lane==0){ red[wid]=s; red[4+wid]=sq; }
  __syncthreads();
  s = red[0]+red[1]+red[2]+red[3]; sq = red[4]+red[5]+red[6]+red[7];
  float mean = s*(1.f/1024.f);
  float inv  = rsqrtf(sq*(1.f/1024.f) - mean*mean + 1e-5f);
  stval(out, base,   (v0-mean)*inv*sc[c]   + bi[c]);
  stval(out, base+1, (v1-mean)*inv*sc[c+1] + bi[c+1]);
  stval(out, base+2, (v2-mean)*inv*sc[c+2] + bi[c+2]);
  stval(out, base+3, (v3-mean)*inv*sc[c+3] + bi[c+3]);
}

// ---------------------------------------------------------------------------
// Fused Emformer attention, bf16 MFMA end-to-end. Closed-form mask.
// R8 structure: block = (bb,hh,ci,qg), 1024 blocks, XCD-affinity remap
// (blk = (g&7) + 8*qg + 32*(g>>3): the 4 qg-blocks sharing a K/V slice land
// on one XCD). R10: K is NOT staged in LDS — QK^T A-frags read directly from
// global (K slice is L2-resident via the affinity remap; tk mapping is
// wave-uniform per mt since sum_cnt ∈ {0,32}). Removes ~9 uint4 staging
// loads + 36 LDS writes per thread and the K-side barrier dependency.
// LDS layout unchanged: S[40][296]@0 (24KB), Q[40][72]@41472B,
// V[nk][66]@23680B (staged after QK, aliases Q — barrier-guarded).
// ---------------------------------------------------------------------------
__global__ __launch_bounds__(256) void attn_fused(
    const uint32_t* __restrict__ qkv32, const uint16_t* __restrict__ hres,
    uint16_t* __restrict__ attn_out) {
  const int blk = blockIdx.x;
  const int qg = (blk>>3)&3;
  const int g  = (blk&7) + ((blk>>5)<<3);
  const int ci = g&7, hh = (g>>3)&15, bb = g>>7;
  const int sum_cnt = (ci<7)?32:0;
  const int bstart = (ci>=1)?128*(ci-1):0;
  const int bend = (ci==7)?1024:128*(ci+1);
  const int nk = sum_cnt + (bend - bstart);
  const int rowbase = bb*1248;
  const int tid = threadIdx.x, wid = tid>>6, lane = tid&63;
  const int fr = lane&15, fc = lane>>4;

  __shared__ __attribute__((aligned(16))) uint16_t sm[30848];  // 61,696 B
  uint16_t* SP16 = sm;                     // S f16 / P bf16 [40][296]
  uint16_t* Q16 = sm + 20736;              // [40][72] bf16
  uint32_t* QD  = (uint32_t*)Q16;          // stride 36 dw
  uint16_t* V16 = sm + 11840;              // [nk][66] bf16 (aliases Q; staged post-QK)
  uint32_t* VD  = (uint32_t*)(sm + 11840); // stride 33 dw

  // ---- stage Q only (K read direct from global in QK^T) ----
  for (int idx = tid; idx < 40*8; idx += 256) {
    int j = idx>>3, q4 = idx&7;
    int ql = qg*40 + j;
    int tq = (ql<32) ? (32*ci+ql) : (224+128*ci+ql-32);
    *(uint4*)&QD[j*36 + q4*4] =
      *(const uint4*)&qkv32[(size_t)(rowbase+tq)*1536 + hh*32 + q4*4];
  }
  __syncthreads();

  // ---- scores: S^T = K . Q^T (m=key, n=query, k=d), K from global ----
  const int n_mt = nk>>4;
  const int qoff[3] = {0,16,24};
  f32x4 accs[5][3];
  #pragma unroll
  for (int a=0;a<5;a++)
    #pragma unroll
    for (int b=0;b<3;b++) accs[a][b] = (f32x4){0.f,0.f,0.f,0.f};
  __builtin_amdgcn_s_setprio(1);
  #pragma unroll
  for (int ks=0; ks<2; ++ks) {
    short8 bq_[3];
    #pragma unroll
    for (int nt=0;nt<3;nt++)
      bq_[nt] = *(const short8*)&Q16[(qoff[nt]+fr)*72 + ks*32 + fc*8];
    #pragma unroll
    for (int t=0;t<5;t++) {
      int mt = wid + 4*t;
      if (mt < n_mt) {
        int mrow = mt*16 + fr;
        int tk = (mrow < sum_cnt) ? (32*ci + mrow) : (224 + bstart + mrow - sum_cnt);
        short8 a_ = *(const short8*)&qkv32[(size_t)(rowbase+tk)*1536 + 512 + hh*32 + ks*16 + fc*4];
        #pragma unroll
        for (int nt=0;nt<3;nt++)
          accs[t][nt] = __builtin_amdgcn_mfma_f32_16x16x32_bf16(a_, bq_[nt], accs[t][nt], 0,0,0);
      }
    }
  }
  __builtin_amdgcn_s_setprio(0);
  __syncthreads();   // Q reads done; S and V regions may be written

  // ---- phase: S <- C-frags (f16), and stage V concurrently ----
  #pragma unroll
  for (int t=0;t<5;t++) {
    int mt = wid + 4*t;
    if (mt < n_mt) {
      #pragma unroll
      for (int nt=0;nt<3;nt++) {
        int q = qoff[nt] + fr;
        #pragma unroll
        for (int r=0;r<4;r++)
          SP16[q*296 + mt*16 + fc*4 + r] = f2h(accs[t][nt][r]*0.125f);
      }
    }
  }
  for (int idx = tid; idx < nk*8; idx += 256) {
    int j = idx>>3, q4 = idx&7;
    int tk = (j < sum_cnt) ? (32*ci + j) : (224 + bstart + (j - sum_cnt));
    uint4 w = *(const uint4*)&qkv32[(size_t)(rowbase+tk)*1536 + 1024 + hh*32 + q4*4];
    uint32_t* dst = &VD[j*33 + q4*4];
    dst[0]=w.x; dst[1]=w.y; dst[2]=w.z; dst[3]=w.w;
  }
  __syncthreads();

  // ---- softmax rows, in place: S(f16) -> P(bf16) ----
  for (int i=0;i<10;i++) {
    int row = wid*10 + i;
    float v[5];
    #pragma unroll
    for (int g2=0;g2<5;g2++){ int k=g2*64+lane; v[g2] = (k<nk) ? h2f(SP16[row*296+k]) : -1e30f; }
    float mx = fmaxf(fmaxf(fmaxf(v[0],v[1]),fmaxf(v[2],v[3])),v[4]);
    #pragma unroll
    for (int off=32; off; off>>=1) mx = fmaxf(mx, __shfl_xor(mx,off));
    float p[5], sum=0.f;
    #pragma unroll
    for (int g2=0;g2<5;g2++){ p[g2] = __expf(v[g2]-mx); if (g2*64+lane>=nk) p[g2]=0.f; sum+=p[g2]; }
    #pragma unroll
    for (int off=32; off; off>>=1) sum += __shfl_xor(sum,off);
    float inv = 1.f/sum;
    #pragma unroll
    for (int g2=0;g2<5;g2++){ int k=g2*64+lane; if (k<nk) SP16[row*296+k] = f2bf(p[g2]*inv); }
  }
  __syncthreads();

  // ---- O = P . V  (m=query, n=d [wave-owned 16], k=key), bf16 MFMA ----
  const int nkt = nk>>5;
  f32x4 acco[3];
  #pragma unroll
  for (int t=0;t<3;t++) acco[t] = (f32x4){0.f,0.f,0.f,0.f};
  const uint16_t* vcol = V16 + wid*16 + fr;
  __builtin_amdgcn_s_setprio(1);
  for (int kt=0; kt<nkt; ++kt) {
    short8 bv_;
    #pragma unroll
    for (int j=0;j<8;j++) bv_[j] = (short)vcol[(kt*32 + fc*8 + j)*66];
    #pragma unroll
    for (int t=0;t<3;t++) {
      short8 a_ = *(const short8*)&SP16[(qoff[t]+fr)*296 + kt*32 + fc*8];
      acco[t] = __builtin_amdgcn_mfma_f32_16x16x32_bf16(a_, bv_, acco[t], 0,0,0);
    }
  }
  __builtin_amdgcn_s_setprio(0);
  // ---- epilogue: + residual (C col = d, row = query) ----
  #pragma unroll
  for (int t=0;t<3;t++) {
    #pragma unroll
    for (int r=0;r<4;r++) {
      bool vq = true;
      if (ci==7 && qg==0 && (qoff[t]+fc*4+r)<32) vq = false;
      if (vq) {
        int qll = qg*40 + qoff[t] + fc*4 + r;
        int tq = (qll<32) ? (32*ci+qll) : (224+128*ci+qll-32);
        size_t addr = (size_t)(rowbase+tq)*1024 + hh*64 + wid*16 + fr;
        attn_out[addr] = f2bf(acco[t][r] + bf1(hres[addr]));
      }
    }
  }
}

// ---------------------------------------------------------------------------
// R8 layer prologue (shrunk): QKV weight transposes (blocks 0..3071), bias
// concat (3072..3083), input LayerNorm rows (3084..5579).
// ---------------------------------------------------------------------------
__global__ void prep_k(const float* __restrict__ Wq, const float* __restrict__ Wk,
                       const float* __restrict__ Wv, const float* __restrict__ bq,
                       const float* __restrict__ bk, const float* __restrict__ bv,
                       uint16_t* __restrict__ wt_qkv, float* __restrict__ bqkv,
                       const void* __restrict__ lnx, int lnx_f32,
                       const float* __restrict__ lnsc, const float* __restrict__ lnbi,
                       uint16_t* __restrict__ lnout) {
  __shared__ float t[32][33];
  const int blk = blockIdx.x;
  const int tx = threadIdx.x, ty = threadIdx.y;
  if (blk >= 3084) {                        // LayerNorm rows
    int row = blk - 3084;
    int tid = ty*32 + tx;
    float* red = &t[0][0];
    if (lnx_f32) ln_body<float,uint16_t>((int)row, tid, (const float*)lnx, lnsc, lnbi, lnout, red);
    else         ln_body<uint16_t,uint16_t>((int)row, tid, (const uint16_t*)lnx, lnsc, lnbi, lnout, red);
    return;
  }
  if (blk >= 3072) {                        // bias concat
    int i = (blk-3072)*256 + ty*32 + tx;
    bqkv[i] = (i<1024) ? bq[i] : ((i<2048) ? bk[i-1024] : bv[i-2048]);
    return;
  }
  int w = blk>>10, tt = blk&1023;
  const float* src = (w==0)?Wq:((w==1)?Wk:Wv);
  uint16_t* dst = wt_qkv + (size_t)w*1048576;
  const int R = 1024, C = 1024;
  const int c0 = (tt&31)*32, r0 = (tt>>5)*32;
  #pragma unroll
  for (int i=0;i<4;i++) t[ty+8*i][tx] = src[(size_t)(r0+ty+8*i)*C + c0+tx];
  __syncthreads();
  #pragma unroll
  for (int i=0;i<4;i++) dst[(size_t)(c0+ty+8*i)*R + r0+tx] = f2bf(t[tx][ty+8*i]);
}

// ---------------------------------------------------------------------------
extern "C" void kernel_launch(void* const* d_in, const int* in_sizes, int n_in,
                              void* d_out, int out_size, void* d_ws, size_t ws_size,
                              hipStream_t stream) {
  const float* input  = (const float*)d_in[0];
  const float* lnin_s = (const float*)d_in[1];
  const float* lnin_b = (const float*)d_in[2];
  const float* Wq = (const float*)d_in[3];
  const float* bq = (const float*)d_in[4];
  const float* Wk = (const float*)d_in[5];
  const float* bk = (const float*)d_in[6];
  const float* Wv = (const float*)d_in[7];
  const float* bv = (const float*)d_in[8];
  const float* ln1_s = (const float*)d_in[9];
  const float* ln1_b = (const float*)d_in[10];
  const float* W1 = (const float*)d_in[11];
  const float* b1 = (const float*)d_in[12];
  const float* W2 = (const float*)d_in[13];
  const float* b2 = (const float*)d_in[14];
  const float* ln2_s = (const float*)d_in[15];
  const float* ln2_b = (const float*)d_in[16];
  // mask d_in[17] unused: Emformer mask is closed-form.

  char* ws = (char*)d_ws;
  uint16_t* wt_qkv = (uint16_t*)(ws + 0);         // bf16 [3072][1024]
  uint16_t* wt_w1  = (uint16_t*)(ws + 6291456);   // bf16 [4096][1024]
  uint16_t* wt_w2  = (uint16_t*)(ws + 14680064);  // bf16 [1024][4096]
  float*    bqkv   = (float*)   (ws + 23068672);  // f32  [3072]
  uint16_t* hbuf   = (uint16_t*)(ws + 23080960);  // bf16 [2560][1024]
  uint16_t* qkvb   = (uint16_t*)(ws + 28323840);  // bf16 [2560][3072]
  uint16_t* attnb  = (uint16_t*)(ws + 44052480);  // bf16 [2560][1024]
  uint16_t* zbuf   = (uint16_t*)(ws + 49295360);  // bf16 [2560][1024]
  float*    pbuf   = (float*)   (ws + 54538240);  // fp32 [2][2560][1024]
  uint16_t* y1b    = hbuf;                        // bf16 [2560][4096] overlays hbuf+qkvb (dead)
  uint16_t* x1b    = zbuf;                        // layer-0 out overlays zbuf (audited r4)
  // peak ws usage: 75,509,760 bytes

  const uint16_t* xcur_bf = x1b;
  for (int l=0; l<2; ++l) {
    prep_k<<<5580, dim3(32,8), 0, stream>>>(Wq+(size_t)l*1048576, Wk+(size_t)l*1048576,
        Wv+(size_t)l*1048576, bq+l*1024, bk+l*1024, bv+l*1024, wt_qkv, bqkv,
        (l==0) ? (const void*)input : (const void*)xcur_bf, (l==0)?1:0,
        lnin_s+l*1024, lnin_b+l*1024, hbuf);

    // QKV GEMM (480 blocks, gm=2 region map) + fused W1/W2 transposes
    gemm_t<128,128,false><<<dim3(8672),256,0,stream>>>(hbuf, wt_qkv, bqkv, qkvb,
        3072, 1024, 0, 2, 24, 20, 480,
        W1+(size_t)l*4194304, W2+(size_t)l*4194304, wt_w1, wt_w2);
    attn_fused<<<1024,256,0,stream>>>((const uint32_t*)qkvb, hbuf, attnb);
    ln_k<uint16_t,uint16_t><<<2496,256,0,stream>>>(attnb, ln1_s+l*1024, ln1_b+l*1024, zbuf);
    // W1: grid 32x20, gm=2 (RM=10, RN=8)
    gemm_t<128,128,false><<<dim3(32,20),256,0,stream>>>(zbuf, wt_w1, b1+l*4096, y1b,
        4096, 1024, 0, 2, 32, 20, 640, nullptr, nullptr, nullptr, nullptr);
    // W2: 128x64 split z=2, legacy 1-D swizzle
    gemm_t<128,64,true><<<dim3(16,20,2),256,0,stream>>>(y1b, wt_w2, nullptr, pbuf,
        1024, 4096, 2048, 0, 16, 20, 320, nullptr, nullptr, nullptr, nullptr);
    if (l==1) ln2_fused<float>   <<<2496,256,0,stream>>>(pbuf, b2+l*1024, attnb, ln2_s+l*1024, ln2_b+l*1024, (float*)d_out);
    else      ln2_fused<uint16_t><<<2496,256,0,stream>>>(pbuf, b2+l*1024, attnb, ln2_s+l*1024, ln2_b+l*1024, x1b);
  }
  (void)in_sizes; (void)n_in; (void)out_size; (void)ws_size;
}

// Round 11
// 471.656 us; speedup vs baseline: 1.1112x; 1.0211x over previous
//
#include <hip/hip_runtime.h>
#include <stdint.h>

typedef __attribute__((ext_vector_type(8))) short short8;
typedef __attribute__((ext_vector_type(4))) float f32x4;

#define DEV __device__ __forceinline__

DEV float bits2f(uint32_t u){ union{uint32_t u;float f;}v; v.u=u; return v.f; }
DEV float bf1(uint16_t s){ return bits2f(((uint32_t)s)<<16); }
DEV uint16_t f2bf(float f){ union{float f;uint32_t u;}v; v.f=f; uint32_t u=v.u;
  return (uint16_t)((u + 0x7fffu + ((u>>16)&1u))>>16); }
DEV uint16_t f2h(float a){ union{_Float16 h; uint16_t u;}v; v.h=(_Float16)a; return v.u; }
DEV float h2f(uint16_t s){ union{uint16_t u; _Float16 h;}v; v.u=s; return (float)v.h; }

DEV float ldval(const float* p, size_t i){ return p[i]; }
DEV float ldval(const uint16_t* p, size_t i){ return bf1(p[i]); }
DEV void stval(float* p, size_t i, float v){ p[i]=v; }
DEV void stval(uint16_t* p, size_t i, float v){ p[i]=f2bf(v); }

DEV void async16(const void* g, void* l){
#if __has_builtin(__builtin_amdgcn_global_load_lds)
  __builtin_amdgcn_global_load_lds((const __attribute__((address_space(1))) void*)g,
                                   (__attribute__((address_space(3))) void*)l, 16, 0, 0);
#else
  int lane = threadIdx.x & 63;
  *(uint4*)((char*)l + lane*16) = *(const uint4*)((const char*)g);
#endif
}

// ---------------------------------------------------------------------------
// GEMM: C[M,N] = A[M,K] @ Bt[N,K]^T (+bias). Tile TM x TN, 4 waves of
// (TM/2)x(TN/2). R3 pipeline: 3-buffer BK=32 rotation, raw s_barrier,
// counted vmcnt (LPS-parameterized). R6 2-D XCD region map (gm>0) /
// 1-D column chunk (gm==0).
// Fused extra blocks (lin >= nG), tmode selects:
//   tmode=0 (R8): W1 transpose tiles (1024x4096, tt<4096) then W2 (4096x1024).
//   tmode=1 (R11): layer-(l+1) QKV transposes (3x 1024x1024, tt<3072) then
//                  bias concat (tt in [3072,3084)). Runs in the W1(l=0)
//                  dispatch's stall cycles; wt_qkv/bqkv(l=0) were consumed
//                  3 dispatches earlier (stream-ordered, audited).
// SPLIT: blockIdx.z K-chunking, fp32 partials at z*2560*N, no bias.
// ---------------------------------------------------------------------------
template<int TM, int TN, bool SPLIT>
__global__ __launch_bounds__(256) void gemm_t(
    const uint16_t* __restrict__ A, const uint16_t* __restrict__ Bt,
    const float* __restrict__ bias, void* __restrict__ Cout,
    int N, int K, int kchunk, int gm, int gx, int gy, int nG, int tmode,
    const float* __restrict__ Tsrc1, const float* __restrict__ Tsrc2,
    const float* __restrict__ Tsrc3,
    uint16_t* __restrict__ Tdst1, uint16_t* __restrict__ Tdst2,
    const float* __restrict__ Bq, const float* __restrict__ Bk,
    const float* __restrict__ Bv, float* __restrict__ bqv) {
  __shared__ uint16_t sA[3][TM*32];
  __shared__ uint16_t sB[3][TN*32];
  constexpr int LPS = TM/64 + TN/64;   // global_load_lds per thread per stage
  const int tid = threadIdx.x;
  const int lin = blockIdx.y*gx + blockIdx.x;

  if (lin >= nG) {                     // ---- fused extra-block work ----
    float (*t)[33] = (float(*)[33])&sA[0][0];
    int tt = lin - nG;
    const float* src; uint16_t* dst; int R, C, c0, r0;
    if (tmode == 0) {
      if (tt < 4096) { src = Tsrc1; dst = Tdst1; R = 1024; C = 4096;
                       c0 = (tt&127)*32; r0 = (tt>>7)*32; }
      else { tt -= 4096; src = Tsrc2; dst = Tdst2; R = 4096; C = 1024;
             c0 = (tt&31)*32; r0 = (tt>>5)*32; }
    } else {
      if (tt >= 3072) {                // bias concat (12 blocks)
        int i = (tt-3072)*256 + tid;
        bqv[i] = (i<1024) ? Bq[i] : ((i<2048) ? Bk[i-1024] : Bv[i-2048]);
        return;
      }
      int w = tt>>10, t2 = tt&1023;
      src = (w==0)?Tsrc1:((w==1)?Tsrc2:Tsrc3);
      dst = Tdst1 + (size_t)w*1048576;
      R = 1024; C = 1024; c0 = (t2&31)*32; r0 = (t2>>5)*32;
    }
    const int tx = tid&31, ty = tid>>5;
    #pragma unroll
    for (int i=0;i<4;i++) t[ty+8*i][tx] = src[(size_t)(r0+ty+8*i)*C + c0+tx];
    __syncthreads();
    #pragma unroll
    for (int i=0;i<4;i++) dst[(size_t)(c0+ty+8*i)*R + r0+tx] = f2bf(t[tx][ty+8*i]);
    return;
  }

  int mt_, nt_;
  if (gm > 0) {
    const int xcd = lin & 7, idx = lin >> 3;
    const int RM = gy / gm;
    const int RN = (gx * gm) >> 3;
    const int rm = xcd % gm, rn = xcd / gm;
    mt_ = rm*RM + idx % RM;
    nt_ = rn*RN + idx / RM;
  } else {
    const int q8 = (gx*gy) >> 3;
    const int swz = (lin & 7)*q8 + (lin >> 3);
    mt_ = swz % gy; nt_ = swz / gy;
  }
  const int m0 = mt_*TM, n0 = nt_*TN;
  const int kb = SPLIT ? blockIdx.z*kchunk : 0;
  const int kend = SPLIT ? kb + kchunk : K;
  const int wid = tid>>6, lane = tid&63;
  constexpr int WM = TM/2, MT = WM/16;
  constexpr int WN = TN/2, NT = WN/16;
  const int wm = (wid&1)*WM, wn = (wid>>1)*WN;
  f32x4 acc[MT][NT];
  #pragma unroll
  for (int a=0;a<MT;a++)
    #pragma unroll
    for (int b=0;b<NT;b++) acc[a][b] = (f32x4){0.f,0.f,0.f,0.f};
  const int lrow = lane>>2;
  const int lcol = (((lane&3) ^ ((lrow>>1)&3)))*8;
  const int fr = lane&15, fc = lane>>4;
  const int rsw = (fc ^ ((fr>>1)&3))*8;    // swizzled read slot

  auto stage = [&](int buf, int k0) {
    #pragma unroll
    for (int j = 0; j < TM/64; ++j) {
      int r0 = wid*(TM/4) + j*16;
      async16(A + (size_t)(m0+r0+lrow)*K + k0 + lcol, &sA[buf][r0*32]);
    }
    #pragma unroll
    for (int j = 0; j < TN/64; ++j) {
      int r0 = wid*(TN/4) + j*16;
      async16(Bt + (size_t)(n0+r0+lrow)*K + k0 + lcol, &sB[buf][r0*32]);
    }
  };

  const int niter = (kend - kb) >> 5;
  stage(0, kb);
  if (niter > 1) stage(1, kb + 32);
  int cur = 0;
  for (int it = 0; it < niter; ++it) {
    if (it+1 < niter) {
      if constexpr (LPS == 4)      asm volatile("s_waitcnt vmcnt(4)" ::: "memory");
      else if constexpr (LPS == 3) asm volatile("s_waitcnt vmcnt(3)" ::: "memory");
      else                         asm volatile("s_waitcnt vmcnt(2)" ::: "memory");
    } else {
      asm volatile("s_waitcnt vmcnt(0)" ::: "memory");
    }
    __builtin_amdgcn_s_barrier();
    __builtin_amdgcn_sched_barrier(0);
    if (it+2 < niter) {
      int b2 = cur+2; if (b2>=3) b2-=3;
      stage(b2, kb + (it+2)*32);
    }
    short8 af[MT], bfv[NT];
    #pragma unroll
    for (int t=0;t<MT;t++) af[t] = *(const short8*)&sA[cur][(wm + t*16 + fr)*32 + rsw];
    #pragma unroll
    for (int t=0;t<NT;t++) bfv[t] = *(const short8*)&sB[cur][(wn + t*16 + fr)*32 + rsw];
    #pragma unroll
    for (int mt=0;mt<MT;mt++)
      #pragma unroll
      for (int nt=0;nt<NT;nt++)
        acc[mt][nt] = __builtin_amdgcn_mfma_f32_16x16x32_bf16(af[mt], bfv[nt], acc[mt][nt], 0,0,0);
    if (++cur == 3) cur = 0;
  }
  const int cl = lane&15, rl = (lane>>4)*4;   // C/D: col=lane&15, row=(lane>>4)*4+reg
  if (SPLIT) {
    float* Pz = (float*)Cout + (size_t)blockIdx.z*2560*N;
    #pragma unroll
    for (int nt=0;nt<NT;nt++) {
      int n = n0 + wn + nt*16 + cl;
      #pragma unroll
      for (int mt=0;mt<MT;mt++)
        #pragma unroll
        for (int r=0;r<4;r++)
          Pz[(size_t)(m0 + wm + mt*16 + rl + r)*N + n] = acc[mt][nt][r];
    }
  } else {
    uint16_t* C = (uint16_t*)Cout;
    #pragma unroll
    for (int nt=0;nt<NT;nt++) {
      int n = n0 + wn + nt*16 + cl;
      float bv = bias ? bias[n] : 0.f;
      #pragma unroll
      for (int mt=0;mt<MT;mt++)
        #pragma unroll
        for (int r=0;r<4;r++)
          C[(size_t)(m0 + wm + mt*16 + rl + r)*N + n] = f2bf(acc[mt][nt][r] + bv);
    }
  }
}

// ---------------------------------------------------------------------------
// LayerNorm body (256-thread flat block, one row of D=1024).
// ---------------------------------------------------------------------------
template<typename TI, typename TO>
DEV void ln_body(int row, int tid, const TI* x, const float* sc, const float* bi,
                 TO* out, float* red) {
  const size_t base = (size_t)row*1024 + tid*4;
  float v0=ldval(x,base), v1=ldval(x,base+1), v2=ldval(x,base+2), v3=ldval(x,base+3);
  float s = v0+v1+v2+v3;
  float sq = v0*v0+v1*v1+v2*v2+v3*v3;
  #pragma unroll
  for (int off=32; off; off>>=1){ s += __shfl_xor(s,off); sq += __shfl_xor(sq,off); }
  int wid=tid>>6, lane=tid&63;
  if (lane==0){ red[wid]=s; red[4+wid]=sq; }
  __syncthreads();
  s = red[0]+red[1]+red[2]+red[3]; sq = red[4]+red[5]+red[6]+red[7];
  float mean = s*(1.f/1024.f);
  float inv  = rsqrtf(sq*(1.f/1024.f) - mean*mean + 1e-5f);
  int c = tid*4;
  stval(out, base,   (v0-mean)*inv*sc[c]   + bi[c]);
  stval(out, base+1, (v1-mean)*inv*sc[c+1] + bi[c+1]);
  stval(out, base+2, (v2-mean)*inv*sc[c+2] + bi[c+2]);
  stval(out, base+3, (v3-mean)*inv*sc[c+3] + bi[c+3]);
}

template<typename TI, typename TO>
__global__ __launch_bounds__(256) void ln_k(const TI* __restrict__ x,
    const float* __restrict__ sc, const float* __restrict__ bi,
    TO* __restrict__ out) {
  __shared__ float red[8];
  ln_body<TI,TO>(blockIdx.x, threadIdx.x, x, sc, bi, out, red);
}

// Fused: y = P[0][row]+P[1][row] + b2 + resid(bf16); out = LN(y). (l=1 path)
template<typename TO>
__global__ __launch_bounds__(256) void ln2_fused(const float* __restrict__ P,
    const float* __restrict__ b2, const uint16_t* __restrict__ resid,
    const float* __restrict__ sc, const float* __restrict__ bi,
    TO* __restrict__ out) {
  const int row = blockIdx.x, tid = threadIdx.x;
  const size_t base = (size_t)row*1024 + tid*4;
  float4 p0 = *(const float4*)(P + base);
  float4 p1 = *(const float4*)(P + (size_t)2560*1024 + base);
  int c = tid*4;
  float v0 = p0.x+p1.x+b2[c]  +bf1(resid[base]);
  float v1 = p0.y+p1.y+b2[c+1]+bf1(resid[base+1]);
  float v2 = p0.z+p1.z+b2[c+2]+bf1(resid[base+2]);
  float v3 = p0.w+p1.w+b2[c+3]+bf1(resid[base+3]);
  float s = v0+v1+v2+v3;
  float sq = v0*v0+v1*v1+v2*v2+v3*v3;
  #pragma unroll
  for (int off=32; off; off>>=1){ s += __shfl_xor(s,off); sq += __shfl_xor(sq,off); }
  __shared__ float red[8];
  int wid=tid>>6, lane=tid&63;
  if (lane==0){ red[wid]=s; red[4+wid]=sq; }
  __syncthreads();
  s = red[0]+red[1]+red[2]+red[3]; sq = red[4]+red[5]+red[6]+red[7];
  float mean = s*(1.f/1024.f);
  float inv  = rsqrtf(sq*(1.f/1024.f) - mean*mean + 1e-5f);
  stval(out, base,   (v0-mean)*inv*sc[c]   + bi[c]);
  stval(out, base+1, (v1-mean)*inv*sc[c+1] + bi[c+1]);
  stval(out, base+2, (v2-mean)*inv*sc[c+2] + bi[c+2]);
  stval(out, base+3, (v3-mean)*inv*sc[c+3] + bi[c+3]);
}

// R11: layer-0 epilogue fused with layer-1 input LN. x1 = LN2(y) is computed
// in registers (full row per block) and immediately re-normalized with the
// layer-1 ln_in params -> hbuf. x1 never materializes (audited: x1 feeds
// only LN-in(l=1)).
__global__ __launch_bounds__(256) void ln2ln_fused(const float* __restrict__ P,
    const float* __restrict__ b2, const uint16_t* __restrict__ resid,
    const float* __restrict__ sc2, const float* __restrict__ bi2,
    const float* __restrict__ sci, const float* __restrict__ bii,
    uint16_t* __restrict__ hout) {
  const int row = blockIdx.x, tid = threadIdx.x;
  const size_t base = (size_t)row*1024 + tid*4;
  float4 p0 = *(const float4*)(P + base);
  float4 p1 = *(const float4*)(P + (size_t)2560*1024 + base);
  int c = tid*4;
  float v0 = p0.x+p1.x+b2[c]  +bf1(resid[base]);
  float v1 = p0.y+p1.y+b2[c+1]+bf1(resid[base+1]);
  float v2 = p0.z+p1.z+b2[c+2]+bf1(resid[base+2]);
  float v3 = p0.w+p1.w+b2[c+3]+bf1(resid[base+3]);
  float s = v0+v1+v2+v3;
  float sq = v0*v0+v1*v1+v2*v2+v3*v3;
  #pragma unroll
  for (int off=32; off; off>>=1){ s += __shfl_xor(s,off); sq += __shfl_xor(sq,off); }
  __shared__ float red[8];
  int wid=tid>>6, lane=tid&63;
  if (lane==0){ red[wid]=s; red[4+wid]=sq; }
  __syncthreads();
  s = red[0]+red[1]+red[2]+red[3]; sq = red[4]+red[5]+red[6]+red[7];
  float mean = s*(1.f/1024.f);
  float inv  = rsqrtf(sq*(1.f/1024.f) - mean*mean + 1e-5f);
  float x0 = (v0-mean)*inv*sc2[c]   + bi2[c];
  float x1 = (v1-mean)*inv*sc2[c+1] + bi2[c+1];
  float x2 = (v2-mean)*inv*sc2[c+2] + bi2[c+2];
  float x3 = (v3-mean)*inv*sc2[c+3] + bi2[c+3];
  // second LN (layer-1 input)
  float s2 = x0+x1+x2+x3;
  float q2 = x0*x0+x1*x1+x2*x2+x3*x3;
  #pragma unroll
  for (int off=32; off; off>>=1){ s2 += __shfl_xor(s2,off); q2 += __shfl_xor(q2,off); }
  __syncthreads();                       // all reads of red done
  if (lane==0){ red[wid]=s2; red[4+wid]=q2; }
  __syncthreads();
  s2 = red[0]+red[1]+red[2]+red[3]; q2 = red[4]+red[5]+red[6]+red[7];
  float mean2 = s2*(1.f/1024.f);
  float inv2  = rsqrtf(q2*(1.f/1024.f) - mean2*mean2 + 1e-5f);
  hout[base]   = f2bf((x0-mean2)*inv2*sci[c]   + bii[c]);
  hout[base+1] = f2bf((x1-mean2)*inv2*sci[c+1] + bii[c+1]);
  hout[base+2] = f2bf((x2-mean2)*inv2*sci[c+2] + bii[c+2]);
  hout[base+3] = f2bf((x3-mean2)*inv2*sci[c+3] + bii[c+3]);
}

// ---------------------------------------------------------------------------
// Fused Emformer attention, bf16 MFMA end-to-end. Closed-form mask.
// R8 structure + R10 K-direct (K read straight from global; L2-resident via
// XCD-affinity remap blk = (g&7) + 8*qg + 32*(g>>3)).
// ---------------------------------------------------------------------------
__global__ __launch_bounds__(256) void attn_fused(
    const uint32_t* __restrict__ qkv32, const uint16_t* __restrict__ hres,
    uint16_t* __restrict__ attn_out) {
  const int blk = blockIdx.x;
  const int qg = (blk>>3)&3;
  const int g  = (blk&7) + ((blk>>5)<<3);
  const int ci = g&7, hh = (g>>3)&15, bb = g>>7;
  const int sum_cnt = (ci<7)?32:0;
  const int bstart = (ci>=1)?128*(ci-1):0;
  const int bend = (ci==7)?1024:128*(ci+1);
  const int nk = sum_cnt + (bend - bstart);
  const int rowbase = bb*1248;
  const int tid = threadIdx.x, wid = tid>>6, lane = tid&63;
  const int fr = lane&15, fc = lane>>4;

  __shared__ __attribute__((aligned(16))) uint16_t sm[30848];  // 61,696 B
  uint16_t* SP16 = sm;                     // S f16 / P bf16 [40][296]
  uint16_t* Q16 = sm + 20736;              // [40][72] bf16
  uint32_t* QD  = (uint32_t*)Q16;          // stride 36 dw
  uint16_t* V16 = sm + 11840;              // [nk][66] bf16 (aliases Q; staged post-QK)
  uint32_t* VD  = (uint32_t*)(sm + 11840); // stride 33 dw

  // ---- stage Q only (K read direct from global in QK^T) ----
  for (int idx = tid; idx < 40*8; idx += 256) {
    int j = idx>>3, q4 = idx&7;
    int ql = qg*40 + j;
    int tq = (ql<32) ? (32*ci+ql) : (224+128*ci+ql-32);
    *(uint4*)&QD[j*36 + q4*4] =
      *(const uint4*)&qkv32[(size_t)(rowbase+tq)*1536 + hh*32 + q4*4];
  }
  __syncthreads();

  // ---- scores: S^T = K . Q^T (m=key, n=query, k=d), K from global ----
  const int n_mt = nk>>4;
  const int qoff[3] = {0,16,24};
  f32x4 accs[5][3];
  #pragma unroll
  for (int a=0;a<5;a++)
    #pragma unroll
    for (int b=0;b<3;b++) accs[a][b] = (f32x4){0.f,0.f,0.f,0.f};
  __builtin_amdgcn_s_setprio(1);
  #pragma unroll
  for (int ks=0; ks<2; ++ks) {
    short8 bq_[3];
    #pragma unroll
    for (int nt=0;nt<3;nt++)
      bq_[nt] = *(const short8*)&Q16[(qoff[nt]+fr)*72 + ks*32 + fc*8];
    #pragma unroll
    for (int t=0;t<5;t++) {
      int mt = wid + 4*t;
      if (mt < n_mt) {
        int mrow = mt*16 + fr;
        int tk = (mrow < sum_cnt) ? (32*ci + mrow) : (224 + bstart + mrow - sum_cnt);
        short8 a_ = *(const short8*)&qkv32[(size_t)(rowbase+tk)*1536 + 512 + hh*32 + ks*16 + fc*4];
        #pragma unroll
        for (int nt=0;nt<3;nt++)
          accs[t][nt] = __builtin_amdgcn_mfma_f32_16x16x32_bf16(a_, bq_[nt], accs[t][nt], 0,0,0);
      }
    }
  }
  __builtin_amdgcn_s_setprio(0);
  __syncthreads();   // Q reads done; S and V regions may be written

  // ---- phase: S <- C-frags (f16), and stage V concurrently ----
  #pragma unroll
  for (int t=0;t<5;t++) {
    int mt = wid + 4*t;
    if (mt < n_mt) {
      #pragma unroll
      for (int nt=0;nt<3;nt++) {
        int q = qoff[nt] + fr;
        #pragma unroll
        for (int r=0;r<4;r++)
          SP16[q*296 + mt*16 + fc*4 + r] = f2h(accs[t][nt][r]*0.125f);
      }
    }
  }
  for (int idx = tid; idx < nk*8; idx += 256) {
    int j = idx>>3, q4 = idx&7;
    int tk = (j < sum_cnt) ? (32*ci + j) : (224 + bstart + (j - sum_cnt));
    uint4 w = *(const uint4*)&qkv32[(size_t)(rowbase+tk)*1536 + 1024 + hh*32 + q4*4];
    uint32_t* dst = &VD[j*33 + q4*4];
    dst[0]=w.x; dst[1]=w.y; dst[2]=w.z; dst[3]=w.w;
  }
  __syncthreads();

  // ---- softmax rows, in place: S(f16) -> P(bf16) ----
  for (int i=0;i<10;i++) {
    int row = wid*10 + i;
    float v[5];
    #pragma unroll
    for (int g2=0;g2<5;g2++){ int k=g2*64+lane; v[g2] = (k<nk) ? h2f(SP16[row*296+k]) : -1e30f; }
    float mx = fmaxf(fmaxf(fmaxf(v[0],v[1]),fmaxf(v[2],v[3])),v[4]);
    #pragma unroll
    for (int off=32; off; off>>=1) mx = fmaxf(mx, __shfl_xor(mx,off));
    float p[5], sum=0.f;
    #pragma unroll
    for (int g2=0;g2<5;g2++){ p[g2] = __expf(v[g2]-mx); if (g2*64+lane>=nk) p[g2]=0.f; sum+=p[g2]; }
    #pragma unroll
    for (int off=32; off; off>>=1) sum += __shfl_xor(sum,off);
    float inv = 1.f/sum;
    #pragma unroll
    for (int g2=0;g2<5;g2++){ int k=g2*64+lane; if (k<nk) SP16[row*296+k] = f2bf(p[g2]*inv); }
  }
  __syncthreads();

  // ---- O = P . V  (m=query, n=d [wave-owned 16], k=key), bf16 MFMA ----
  const int nkt = nk>>5;
  f32x4 acco[3];
  #pragma unroll
  for (int t=0;t<3;t++) acco[t] = (f32x4){0.f,0.f,0.f,0.f};
  const uint16_t* vcol = V16 + wid*16 + fr;
  __builtin_amdgcn_s_setprio(1);
  for (int kt=0; kt<nkt; ++kt) {
    short8 bv_;
    #pragma unroll
    for (int j=0;j<8;j++) bv_[j] = (short)vcol[(kt*32 + fc*8 + j)*66];
    #pragma unroll
    for (int t=0;t<3;t++) {
      short8 a_ = *(const short8*)&SP16[(qoff[t]+fr)*296 + kt*32 + fc*8];
      acco[t] = __builtin_amdgcn_mfma_f32_16x16x32_bf16(a_, bv_, acco[t], 0,0,0);
    }
  }
  __builtin_amdgcn_s_setprio(0);
  // ---- epilogue: + residual (C col = d, row = query) ----
  #pragma unroll
  for (int t=0;t<3;t++) {
    #pragma unroll
    for (int r=0;r<4;r++) {
      bool vq = true;
      if (ci==7 && qg==0 && (qoff[t]+fc*4+r)<32) vq = false;
      if (vq) {
        int qll = qg*40 + qoff[t] + fc*4 + r;
        int tq = (qll<32) ? (32*ci+qll) : (224+128*ci+qll-32);
        size_t addr = (size_t)(rowbase+tq)*1024 + hh*64 + wid*16 + fr;
        attn_out[addr] = f2bf(acco[t][r] + bf1(hres[addr]));
      }
    }
  }
}

// ---------------------------------------------------------------------------
// Layer-0 prologue: QKV weight transposes (blocks 0..3071), bias concat
// (3072..3083), input LayerNorm rows (3084..5579). Layer-1's prologue work
// is fused elsewhere (R11): LN -> ln2ln_fused; transposes+bias -> W1(l=0).
// ---------------------------------------------------------------------------
__global__ void prep_k(const float* __restrict__ Wq, const float* __restrict__ Wk,
                       const float* __restrict__ Wv, const float* __restrict__ bq,
                       const float* __restrict__ bk, const float* __restrict__ bv,
                       uint16_t* __restrict__ wt_qkv, float* __restrict__ bqkv,
                       const float* __restrict__ lnx,
                       const float* __restrict__ lnsc, const float* __restrict__ lnbi,
                       uint16_t* __restrict__ lnout) {
  __shared__ float t[32][33];
  const int blk = blockIdx.x;
  const int tx = threadIdx.x, ty = threadIdx.y;
  if (blk >= 3084) {                        // LayerNorm rows (f32 input)
    int row = blk - 3084;
    int tid = ty*32 + tx;
    float* red = &t[0][0];
    ln_body<float,uint16_t>((int)row, tid, lnx, lnsc, lnbi, lnout, red);
    return;
  }
  if (blk >= 3072) {                        // bias concat
    int i = (blk-3072)*256 + ty*32 + tx;
    bqkv[i] = (i<1024) ? bq[i] : ((i<2048) ? bk[i-1024] : bv[i-2048]);
    return;
  }
  int w = blk>>10, tt = blk&1023;
  const float* src = (w==0)?Wq:((w==1)?Wk:Wv);
  uint16_t* dst = wt_qkv + (size_t)w*1048576;
  const int R = 1024, C = 1024;
  const int c0 = (tt&31)*32, r0 = (tt>>5)*32;
  #pragma unroll
  for (int i=0;i<4;i++) t[ty+8*i][tx] = src[(size_t)(r0+ty+8*i)*C + c0+tx];
  __syncthreads();
  #pragma unroll
  for (int i=0;i<4;i++) dst[(size_t)(c0+ty+8*i)*R + r0+tx] = f2bf(t[tx][ty+8*i]);
}

// ---------------------------------------------------------------------------
extern "C" void kernel_launch(void* const* d_in, const int* in_sizes, int n_in,
                              void* d_out, int out_size, void* d_ws, size_t ws_size,
                              hipStream_t stream) {
  const float* input  = (const float*)d_in[0];
  const float* lnin_s = (const float*)d_in[1];
  const float* lnin_b = (const float*)d_in[2];
  const float* Wq = (const float*)d_in[3];
  const float* bq = (const float*)d_in[4];
  const float* Wk = (const float*)d_in[5];
  const float* bk = (const float*)d_in[6];
  const float* Wv = (const float*)d_in[7];
  const float* bv = (const float*)d_in[8];
  const float* ln1_s = (const float*)d_in[9];
  const float* ln1_b = (const float*)d_in[10];
  const float* W1 = (const float*)d_in[11];
  const float* b1 = (const float*)d_in[12];
  const float* W2 = (const float*)d_in[13];
  const float* b2 = (const float*)d_in[14];
  const float* ln2_s = (const float*)d_in[15];
  const float* ln2_b = (const float*)d_in[16];
  // mask d_in[17] unused: Emformer mask is closed-form.

  char* ws = (char*)d_ws;
  uint16_t* wt_qkv = (uint16_t*)(ws + 0);         // bf16 [3072][1024]
  uint16_t* wt_w1  = (uint16_t*)(ws + 6291456);   // bf16 [4096][1024]
  uint16_t* wt_w2  = (uint16_t*)(ws + 14680064);  // bf16 [1024][4096]
  float*    bqkv   = (float*)   (ws + 23068672);  // f32  [3072]
  uint16_t* hbuf   = (uint16_t*)(ws + 23080960);  // bf16 [2560][1024]
  uint16_t* qkvb   = (uint16_t*)(ws + 28323840);  // bf16 [2560][3072]
  uint16_t* attnb  = (uint16_t*)(ws + 44052480);  // bf16 [2560][1024]
  uint16_t* zbuf   = (uint16_t*)(ws + 49295360);  // bf16 [2560][1024]
  float*    pbuf   = (float*)   (ws + 54538240);  // fp32 [2][2560][1024]
  uint16_t* y1b    = hbuf;                        // bf16 [2560][4096] overlays hbuf+qkvb (dead)
  // peak ws usage: 75,509,760 bytes

  // ---------------- layer 0 ----------------
  prep_k<<<5580, dim3(32,8), 0, stream>>>(Wq, Wk, Wv, bq, bk, bv, wt_qkv, bqkv,
      input, lnin_s, lnin_b, hbuf);

  // QKV GEMM (480 blocks, gm=2) + fused W1/W2(l=0) transposes
  gemm_t<128,128,false><<<dim3(8672),256,0,stream>>>(hbuf, wt_qkv, bqkv, qkvb,
      3072, 1024, 0, 2, 24, 20, 480, 0,
      W1, W2, nullptr, wt_w1, wt_w2, nullptr, nullptr, nullptr, nullptr);
  attn_fused<<<1024,256,0,stream>>>((const uint32_t*)qkvb, hbuf, attnb);
  ln_k<uint16_t,uint16_t><<<2496,256,0,stream>>>(attnb, ln1_s, ln1_b, zbuf);
  // W1(l=0): 640 GEMM blocks (gm=2) + fused QKV(l=1) transposes + bias(l=1)
  gemm_t<128,128,false><<<dim3(3724),256,0,stream>>>(zbuf, wt_w1, b1, y1b,
      4096, 1024, 0, 2, 32, 20, 640, 1,
      Wq+1048576, Wk+1048576, Wv+1048576, wt_qkv, nullptr,
      bq+1024, bk+1024, bv+1024, bqkv);
  gemm_t<128,64,true><<<dim3(16,20,2),256,0,stream>>>(y1b, wt_w2, nullptr, pbuf,
      1024, 4096, 2048, 0, 16, 20, 320, 0,
      nullptr, nullptr, nullptr, nullptr, nullptr, nullptr, nullptr, nullptr, nullptr);
  // epilogue: LN2(l=0) fused with LN-in(l=1) -> hbuf (x1 never materializes)
  ln2ln_fused<<<2496,256,0,stream>>>(pbuf, b2, attnb, ln2_s, ln2_b,
      lnin_s+1024, lnin_b+1024, hbuf);

  // ---------------- layer 1 ----------------
  gemm_t<128,128,false><<<dim3(8672),256,0,stream>>>(hbuf, wt_qkv, bqkv, qkvb,
      3072, 1024, 0, 2, 24, 20, 480, 0,
      W1+4194304, W2+4194304, nullptr, wt_w1, wt_w2, nullptr, nullptr, nullptr, nullptr);
  attn_fused<<<1024,256,0,stream>>>((const uint32_t*)qkvb, hbuf, attnb);
  ln_k<uint16_t,uint16_t><<<2496,256,0,stream>>>(attnb, ln1_s+1024, ln1_b+1024, zbuf);
  gemm_t<128,128,false><<<dim3(32,20),256,0,stream>>>(zbuf, wt_w1, b1+4096, y1b,
      4096, 1024, 0, 2, 32, 20, 640, 0,
      nullptr, nullptr, nullptr, nullptr, nullptr, nullptr, nullptr, nullptr, nullptr);
  gemm_t<128,64,true><<<dim3(16,20,2),256,0,stream>>>(y1b, wt_w2, nullptr, pbuf,
      1024, 4096, 2048, 0, 16, 20, 320, 0,
      nullptr, nullptr, nullptr, nullptr, nullptr, nullptr, nullptr, nullptr, nullptr);
  ln2_fused<float><<<2496,256,0,stream>>>(pbuf, b2+1024, attnb, ln2_s+1024, ln2_b+1024,
      (float*)d_out);

  (void)in_sizes; (void)n_in; (void)out_size; (void)ws_size;
}